// Round 1
// baseline (124.168 us; speedup 1.0000x reference)
//
#include <hip/hip_runtime.h>
#include <stdint.h>

#define VOCAB 32000
#define KDIM  2048   // 2*HIDDEN
#define NDIM  1024   // HIDDEN
#define MTOK  16384  // 4*4096

typedef __bf16 bf16x8 __attribute__((ext_vector_type(8)));
typedef float  f32x4  __attribute__((ext_vector_type(4)));

__device__ __forceinline__ unsigned short f2bf(float f) {
    union { float f; uint32_t u; } v; v.f = f;
    uint32_t u = v.u;
    uint32_t r = (u + 0x7FFFu + ((u >> 16) & 1u)) >> 16;  // RNE
    return (unsigned short)r;
}

// ---------------------------------------------------------------------------
// One-time (per launch) transpose+convert: W1 [K][N] f32 -> W1T [N][K] bf16
// ---------------------------------------------------------------------------
__global__ void w1_transpose_kernel(const float* __restrict__ W1,
                                    unsigned short* __restrict__ W1T) {
    __shared__ unsigned short tile[32][33];  // +1 pad kills bank conflicts
    const int k0 = blockIdx.x * 32;
    const int n0 = blockIdx.y * 32;
    const int tx = threadIdx.x;  // 0..31
    const int ty = threadIdx.y;  // 0..7
#pragma unroll
    for (int i = 0; i < 4; ++i) {
        int kl = ty + i * 8;
        tile[kl][tx] = f2bf(W1[(size_t)(k0 + kl) * NDIM + n0 + tx]);
    }
    __syncthreads();
#pragma unroll
    for (int i = 0; i < 4; ++i) {
        int nl = ty + i * 8;
        W1T[(size_t)(n0 + nl) * KDIM + k0 + tx] = tile[tx][nl];
    }
}

// ---------------------------------------------------------------------------
// Gather + GEMM: out[m][n] = sum_k W0[idx[m]][k] * W1[k][n], masked + scaled.
// 128x128 tile, BK=64, 4 waves (2x2), each wave 64x64 via 4x4 frags of
// mfma_f32_16x16x32_bf16. A and B tiles stored k-contiguous in LDS with
// XOR swizzle (byte ^= (row&7)<<4) to break the 128B-row-stride conflict.
// ---------------------------------------------------------------------------
template <bool USE_WS>
__global__ __launch_bounds__(256)
void emb_gemm_kernel(const int* __restrict__ idx,
                     const float* __restrict__ W0,
                     const float* __restrict__ W1,           // [K][N] f32
                     const unsigned short* __restrict__ W1T, // [N][K] bf16
                     float* __restrict__ out) {
    __shared__ char A_lds[128 * 64 * 2];  // [m][k] bf16, swizzled rows (128B)
    __shared__ char B_lds[128 * 64 * 2];  // [n][k] bf16, swizzled rows (128B)

    const int tid  = threadIdx.x;
    const int lane = tid & 63;
    const int wave = tid >> 6;
    const int wm = wave >> 1;      // 0..1
    const int wn = wave & 1;       // 0..1
    const int m0 = blockIdx.x * 128;
    const int n0 = blockIdx.y * 128;

    // Loop-invariant gather bases: thread stages 8 A-rows, 1 float4 per row.
    const float* aSrc[8];
    int arow[8];
#pragma unroll
    for (int it = 0; it < 8; ++it) {
        int r = it * 16 + (tid >> 4);
        arow[it] = r;
        int token = idx[m0 + r];
        aSrc[it] = W0 + (size_t)token * KDIM;
    }
    const int acol4 = tid & 15;  // which float4 (of 16) within the 64-k chunk

    f32x4 acc[4][4] = {};

    for (int k0 = 0; k0 < KDIM; k0 += 64) {
        // ---- stage A (gathered rows, fp32 -> bf16) ----
#pragma unroll
        for (int it = 0; it < 8; ++it) {
            const int r = arow[it];
            const float4 v = *(const float4*)(aSrc[it] + k0 + acol4 * 4);
            uint32_t lo = (uint32_t)f2bf(v.x) | ((uint32_t)f2bf(v.y) << 16);
            uint32_t hi = (uint32_t)f2bf(v.z) | ((uint32_t)f2bf(v.w) << 16);
            int byte = r * 128 + acol4 * 8;
            byte ^= (r & 7) << 4;
            uint2 pk; pk.x = lo; pk.y = hi;
            *(uint2*)(A_lds + byte) = pk;
        }
        // ---- stage B ----
        if (USE_WS) {
            // W1T rows are k-contiguous bf16: 16B vector copy, coalesced.
#pragma unroll
            for (int it = 0; it < 4; ++it) {
                const int n = it * 32 + (tid >> 3);  // 0..127
                const int c = tid & 7;               // 16B chunk in 128B row
                uint4 v = *(const uint4*)(W1T + (size_t)(n0 + n) * KDIM + k0 + c * 8);
                int byte = n * 128 + c * 16;
                byte ^= (n & 7) << 4;
                *(uint4*)(B_lds + byte) = v;
            }
        } else {
            // Transpose-on-stage from W1 [k][n]: coalesced f32 reads along n,
            // scalar bf16 LDS writes (swizzle keeps conflicts ~4-way).
#pragma unroll
            for (int it = 0; it < 8; ++it) {
                const int k  = it * 8 + (tid >> 5);   // 0..63
                const int n4 = (tid & 31) * 4;        // 0..124
                const float4 v = *(const float4*)(W1 + (size_t)(k0 + k) * NDIM + n0 + n4);
                unsigned short h[4] = { f2bf(v.x), f2bf(v.y), f2bf(v.z), f2bf(v.w) };
#pragma unroll
                for (int i = 0; i < 4; ++i) {
                    const int n = n4 + i;
                    int byte = n * 128 + k * 2;
                    byte ^= (n & 7) << 4;
                    *(unsigned short*)(B_lds + byte) = h[i];
                }
            }
        }
        __syncthreads();

        // ---- compute: 2 k-steps of 32, 4x4 fragments ----
#pragma unroll
        for (int ks = 0; ks < 2; ++ks) {
            const int kb = ks * 64 + (lane >> 4) * 16;  // byte offset along k
            bf16x8 af[4], bfr[4];
#pragma unroll
            for (int mi = 0; mi < 4; ++mi) {
                const int r = wm * 64 + mi * 16 + (lane & 15);
                int byte = r * 128 + kb;
                byte ^= (r & 7) << 4;
                af[mi] = *(const bf16x8*)(A_lds + byte);
            }
#pragma unroll
            for (int ni = 0; ni < 4; ++ni) {
                const int n = wn * 64 + ni * 16 + (lane & 15);
                int byte = n * 128 + kb;
                byte ^= (n & 7) << 4;
                bfr[ni] = *(const bf16x8*)(B_lds + byte);
            }
#pragma unroll
            for (int mi = 0; mi < 4; ++mi)
#pragma unroll
                for (int ni = 0; ni < 4; ++ni)
                    acc[mi][ni] = __builtin_amdgcn_mfma_f32_16x16x32_bf16(
                        af[mi], bfr[ni], acc[mi][ni], 0, 0, 0);
        }
        __syncthreads();
    }

    // ---- epilogue: mask (token==0 -> 0) and scale by 32 = sqrt(1024) ----
    const int col  = lane & 15;
    const int rowq = (lane >> 4) * 4;
#pragma unroll
    for (int mi = 0; mi < 4; ++mi) {
#pragma unroll
        for (int r = 0; r < 4; ++r) {
            const int m = m0 + wm * 64 + mi * 16 + rowq + r;
            const float msk = (idx[m] != 0) ? 32.0f : 0.0f;
#pragma unroll
            for (int ni = 0; ni < 4; ++ni) {
                const int n = n0 + wn * 64 + ni * 16 + col;
                out[(size_t)m * NDIM + n] = acc[mi][ni][r] * msk;
            }
        }
    }
}

extern "C" void kernel_launch(void* const* d_in, const int* in_sizes, int n_in,
                              void* d_out, int out_size, void* d_ws, size_t ws_size,
                              hipStream_t stream) {
    const int*   idx = (const int*)d_in[0];
    const float* W0  = (const float*)d_in[1];
    const float* W1  = (const float*)d_in[2];
    float*       out = (float*)d_out;

    dim3 grid(MTOK / 128, NDIM / 128);  // 128 x 8 = 1024 blocks
    const size_t w1t_bytes = (size_t)KDIM * NDIM * 2;

    if (ws_size >= w1t_bytes) {
        unsigned short* W1T = (unsigned short*)d_ws;
        dim3 tgrid(KDIM / 32, NDIM / 32);
        w1_transpose_kernel<<<tgrid, dim3(32, 8), 0, stream>>>(W1, W1T);
        emb_gemm_kernel<true><<<grid, 256, 0, stream>>>(idx, W0, W1, W1T, out);
    } else {
        emb_gemm_kernel<false><<<grid, 256, 0, stream>>>(idx, W0, W1, nullptr, out);
    }
}

// Round 2
// 121.624 us; speedup vs baseline: 1.0209x; 1.0209x over previous
//
#include <hip/hip_runtime.h>
#include <stdint.h>

#define VOCAB 32000
#define KDIM  2048   // 2*HIDDEN
#define NDIM  1024   // HIDDEN
#define MTOK  16384  // 4*4096

typedef __bf16 bf16x8 __attribute__((ext_vector_type(8)));
typedef float  f32x4  __attribute__((ext_vector_type(4)));

// Compiler-lowered f32->bf16 pair (RNE). Guide m240: do NOT hand-write cvt_pk.
__device__ __forceinline__ uint32_t pkbf(float a, float b) {
    union { __bf16 h[2]; uint32_t u; } r;
    r.h[0] = (__bf16)a; r.h[1] = (__bf16)b;
    return r.u;
}

__device__ __forceinline__ unsigned short f2bf(float f) {  // fallback path only
    union { float f; uint32_t u; } v; v.f = f;
    uint32_t u = v.u;
    return (unsigned short)((u + 0x7FFFu + ((u >> 16) & 1u)) >> 16);
}

// width-16 global->LDS DMA: per-lane global src, wave-uniform LDS base,
// HW writes lane l's 16B at base + l*16.
__device__ __forceinline__ void gload_lds16(const void* g, void* l) {
    __builtin_amdgcn_global_load_lds(
        (const __attribute__((address_space(1))) uint32_t*)g,
        (__attribute__((address_space(3))) uint32_t*)l,
        16, 0, 0);
}

// ---------------------------------------------------------------------------
// One-time (per launch) transpose+convert: W1 [K][N] f32 -> W1T [N][K] bf16
// ---------------------------------------------------------------------------
__global__ void w1_transpose_kernel(const float* __restrict__ W1,
                                    unsigned short* __restrict__ W1T) {
    __shared__ unsigned short tile[32][33];
    const int k0 = blockIdx.x * 32;
    const int n0 = blockIdx.y * 32;
    const int tx = threadIdx.x;  // 0..31
    const int ty = threadIdx.y;  // 0..7
#pragma unroll
    for (int i = 0; i < 4; ++i) {
        int kl = ty + i * 8;
        tile[kl][tx] = __builtin_bit_cast(unsigned short,
                            (__bf16)W1[(size_t)(k0 + kl) * NDIM + n0 + tx]);
    }
    __syncthreads();
#pragma unroll
    for (int i = 0; i < 4; ++i) {
        int nl = ty + i * 8;
        W1T[(size_t)(n0 + nl) * KDIM + k0 + tx] = tile[tx][nl];
    }
}

// ---------------------------------------------------------------------------
// Main fused gather-GEMM (ws path). 128x128 tile, BK=64, 4 waves (2x2),
// mfma_f32_16x16x32_bf16, XOR swizzle byte^=(row&7)<<4 on both LDS tiles.
//   A: reg-staged gather from W0 (fp32) with compiler bf16 casts; next-chunk
//      prefetch issued after the barrier so it hides under the MFMA phase.
//   B: global_load_lds width 16 from W1T (bf16), linear LDS dest with
//      pre-swizzled SOURCE chunk (rule 21), swizzled ds_read.
// ---------------------------------------------------------------------------
__global__ __launch_bounds__(256)
void emb_gemm_ws(const int* __restrict__ idx,
                 const float* __restrict__ W0,
                 const unsigned short* __restrict__ W1T,
                 float* __restrict__ out) {
    __shared__ char A_lds[128 * 128];  // 128 rows x 64 bf16 (128B), swizzled
    __shared__ char B_lds[128 * 128];

    const int tid  = threadIdx.x;
    const int lane = tid & 63;
    const int wav  = tid >> 6;
    const int wm = wav >> 1;
    const int wn = wav & 1;
    const int m0 = blockIdx.x * 128;
    const int n0 = blockIdx.y * 128;

    // ---- A gather setup: each thread stages 8 rows x 16B (4 f32) ----
    const int acol = tid & 15;  // which float4 within the 64-wide K chunk
    const float* aPtr[8];
    int abyte[8];
#pragma unroll
    for (int it = 0; it < 8; ++it) {
        const int r = it * 16 + (tid >> 4);
        const int token = idx[m0 + r];
        aPtr[it]  = W0 + (size_t)token * KDIM + acol * 4;
        abyte[it] = (r * 128 + acol * 8) ^ ((r & 7) << 4);
    }

    // ---- B staging setup: 4 global_load_lds per wave per K-step ----
    const int brin = lane >> 3;           // row within 8-row group
    const int bch  = (lane & 7) ^ brin;   // pre-swizzled 16B chunk index
    const unsigned short* bPtr[4];
    int bbase[4];
#pragma unroll
    for (int i = 0; i < 4; ++i) {
        const int rg = wav * 32 + i * 8;  // wave-uniform group base row
        bPtr[i]  = W1T + (size_t)(n0 + rg + brin) * KDIM + bch * 8;
        bbase[i] = rg * 128;
    }

    // prefetch first A chunk
    f32x4 apre[8];
#pragma unroll
    for (int it = 0; it < 8; ++it) apre[it] = *(const f32x4*)(aPtr[it]);

    f32x4 acc[4][4] = {};

    for (int k0 = 0; k0 < KDIM; k0 += 64) {
        // ---- stage A from prefetched regs (convert f32->bf16) ----
#pragma unroll
        for (int it = 0; it < 8; ++it) {
            uint2 pk;
            pk.x = pkbf(apre[it][0], apre[it][1]);
            pk.y = pkbf(apre[it][2], apre[it][3]);
            *(uint2*)(A_lds + abyte[it]) = pk;
        }
        // ---- stage B direct to LDS ----
#pragma unroll
        for (int i = 0; i < 4; ++i)
            gload_lds16(bPtr[i] + k0, B_lds + bbase[i]);

        __syncthreads();  // compiler drains vmcnt+lgkmcnt here

        // ---- prefetch next A chunk; hides under MFMA below ----
        const int kn = (k0 + 64 < KDIM) ? (k0 + 64) : 0;
#pragma unroll
        for (int it = 0; it < 8; ++it)
            apre[it] = *(const f32x4*)(aPtr[it] + kn);

        // ---- MFMA: 2 k-substeps of 32, 4x4 fragments per wave ----
#pragma unroll
        for (int ks = 0; ks < 2; ++ks) {
            const int kb = ks * 64 + (lane >> 4) * 16;
            bf16x8 af[4], bfr[4];
#pragma unroll
            for (int mi = 0; mi < 4; ++mi) {
                const int r = wm * 64 + mi * 16 + (lane & 15);
                af[mi] = *(const bf16x8*)(A_lds + ((r * 128 + kb) ^ ((r & 7) << 4)));
            }
#pragma unroll
            for (int ni = 0; ni < 4; ++ni) {
                const int n = wn * 64 + ni * 16 + (lane & 15);
                bfr[ni] = *(const bf16x8*)(B_lds + ((n * 128 + kb) ^ ((n & 7) << 4)));
            }
#pragma unroll
            for (int mi = 0; mi < 4; ++mi)
#pragma unroll
                for (int ni = 0; ni < 4; ++ni)
                    acc[mi][ni] = __builtin_amdgcn_mfma_f32_16x16x32_bf16(
                        af[mi], bfr[ni], acc[mi][ni], 0, 0, 0);
        }
        __syncthreads();
    }

    // ---- epilogue: mask (token==0 -> 0) and scale by 32 = sqrt(1024) ----
    const int col  = lane & 15;
    const int rowq = (lane >> 4) * 4;
#pragma unroll
    for (int mi = 0; mi < 4; ++mi) {
#pragma unroll
        for (int r = 0; r < 4; ++r) {
            const int m = m0 + wm * 64 + mi * 16 + rowq + r;
            const float msk = (idx[m] != 0) ? 32.0f : 0.0f;
#pragma unroll
            for (int ni = 0; ni < 4; ++ni) {
                const int n = n0 + wn * 64 + ni * 16 + col;
                out[(size_t)m * NDIM + n] = acc[mi][ni][r] * msk;
            }
        }
    }
}

// ---------------------------------------------------------------------------
// Fallback (ws too small): transpose-on-stage from W1 fp32 (round-1 path).
// ---------------------------------------------------------------------------
__global__ __launch_bounds__(256)
void emb_gemm_nows(const int* __restrict__ idx,
                   const float* __restrict__ W0,
                   const float* __restrict__ W1,
                   float* __restrict__ out) {
    __shared__ char A_lds[128 * 128];
    __shared__ char B_lds[128 * 128];

    const int tid  = threadIdx.x;
    const int lane = tid & 63;
    const int wav  = tid >> 6;
    const int wm = wav >> 1;
    const int wn = wav & 1;
    const int m0 = blockIdx.x * 128;
    const int n0 = blockIdx.y * 128;

    const float* aSrc[8];
    int arow[8];
#pragma unroll
    for (int it = 0; it < 8; ++it) {
        int r = it * 16 + (tid >> 4);
        arow[it] = r;
        aSrc[it] = W0 + (size_t)idx[m0 + r] * KDIM;
    }
    const int acol4 = tid & 15;

    f32x4 acc[4][4] = {};

    for (int k0 = 0; k0 < KDIM; k0 += 64) {
#pragma unroll
        for (int it = 0; it < 8; ++it) {
            const int r = arow[it];
            const float4 v = *(const float4*)(aSrc[it] + k0 + acol4 * 4);
            uint2 pk;
            pk.x = pkbf(v.x, v.y);
            pk.y = pkbf(v.z, v.w);
            *(uint2*)(A_lds + ((r * 128 + acol4 * 8) ^ ((r & 7) << 4))) = pk;
        }
#pragma unroll
        for (int it = 0; it < 8; ++it) {
            const int k  = it * 8 + (tid >> 5);
            const int n4 = (tid & 31) * 4;
            const float4 v = *(const float4*)(W1 + (size_t)(k0 + k) * NDIM + n0 + n4);
            unsigned short h[4] = { f2bf(v.x), f2bf(v.y), f2bf(v.z), f2bf(v.w) };
#pragma unroll
            for (int i = 0; i < 4; ++i) {
                const int n = n4 + i;
                *(unsigned short*)(B_lds + ((n * 128 + k * 2) ^ ((n & 7) << 4))) = h[i];
            }
        }
        __syncthreads();

#pragma unroll
        for (int ks = 0; ks < 2; ++ks) {
            const int kb = ks * 64 + (lane >> 4) * 16;
            bf16x8 af[4], bfr[4];
#pragma unroll
            for (int mi = 0; mi < 4; ++mi) {
                const int r = wm * 64 + mi * 16 + (lane & 15);
                af[mi] = *(const bf16x8*)(A_lds + ((r * 128 + kb) ^ ((r & 7) << 4)));
            }
#pragma unroll
            for (int ni = 0; ni < 4; ++ni) {
                const int n = wn * 64 + ni * 16 + (lane & 15);
                bfr[ni] = *(const bf16x8*)(B_lds + ((n * 128 + kb) ^ ((n & 7) << 4)));
            }
#pragma unroll
            for (int mi = 0; mi < 4; ++mi)
#pragma unroll
                for (int ni = 0; ni < 4; ++ni)
                    acc[mi][ni] = __builtin_amdgcn_mfma_f32_16x16x32_bf16(
                        af[mi], bfr[ni], acc[mi][ni], 0, 0, 0);
        }
        __syncthreads();
    }

    const int col  = lane & 15;
    const int rowq = (lane >> 4) * 4;
#pragma unroll
    for (int mi = 0; mi < 4; ++mi) {
#pragma unroll
        for (int r = 0; r < 4; ++r) {
            const int m = m0 + wm * 64 + mi * 16 + rowq + r;
            const float msk = (idx[m] != 0) ? 32.0f : 0.0f;
#pragma unroll
            for (int ni = 0; ni < 4; ++ni) {
                const int n = n0 + wn * 64 + ni * 16 + col;
                out[(size_t)m * NDIM + n] = acc[mi][ni][r] * msk;
            }
        }
    }
}

extern "C" void kernel_launch(void* const* d_in, const int* in_sizes, int n_in,
                              void* d_out, int out_size, void* d_ws, size_t ws_size,
                              hipStream_t stream) {
    const int*   idx = (const int*)d_in[0];
    const float* W0  = (const float*)d_in[1];
    const float* W1  = (const float*)d_in[2];
    float*       out = (float*)d_out;

    dim3 grid(MTOK / 128, NDIM / 128);  // 128 x 8 = 1024 blocks
    const size_t w1t_bytes = (size_t)KDIM * NDIM * 2;

    if (ws_size >= w1t_bytes) {
        unsigned short* W1T = (unsigned short*)d_ws;
        dim3 tgrid(KDIM / 32, NDIM / 32);
        w1_transpose_kernel<<<tgrid, dim3(32, 8), 0, stream>>>(W1, W1T);
        emb_gemm_ws<<<grid, 256, 0, stream>>>(idx, W0, W1T, out);
    } else {
        emb_gemm_nows<<<grid, 256, 0, stream>>>(idx, W0, W1, out);
    }
}

// Round 3
// 114.760 us; speedup vs baseline: 1.0820x; 1.0598x over previous
//
#include <hip/hip_runtime.h>
#include <stdint.h>

#define VOCAB 32000
#define KDIM  2048   // 2*HIDDEN
#define NDIM  1024   // HIDDEN
#define MTOK  16384  // 4*4096

typedef __bf16 bf16x8 __attribute__((ext_vector_type(8)));
typedef float  f32x4  __attribute__((ext_vector_type(4)));

// Compiler-lowered f32->bf16 pair (RNE).
__device__ __forceinline__ uint32_t pkbf(float a, float b) {
    union { __bf16 h[2]; uint32_t u; } r;
    r.h[0] = (__bf16)a; r.h[1] = (__bf16)b;
    return r.u;
}

__device__ __forceinline__ unsigned short f2bf(float f) {  // fallback path only
    union { float f; uint32_t u; } v; v.f = f;
    uint32_t u = v.u;
    return (unsigned short)((u + 0x7FFFu + ((u >> 16) & 1u)) >> 16);
}

// width-16 global->LDS DMA: per-lane global src, wave-uniform LDS base.
__device__ __forceinline__ void gload_lds16(const void* g, void* l) {
    __builtin_amdgcn_global_load_lds(
        (const __attribute__((address_space(1))) uint32_t*)g,
        (__attribute__((address_space(3))) uint32_t*)l,
        16, 0, 0);
}

// ---------------------------------------------------------------------------
// One-time transpose+convert: W1 [K][N] f32 -> W1T [N][K] bf16
// ---------------------------------------------------------------------------
__global__ void w1_transpose_kernel(const float* __restrict__ W1,
                                    unsigned short* __restrict__ W1T) {
    __shared__ unsigned short tile[32][33];
    const int k0 = blockIdx.x * 32;
    const int n0 = blockIdx.y * 32;
    const int tx = threadIdx.x;  // 0..31
    const int ty = threadIdx.y;  // 0..7
#pragma unroll
    for (int i = 0; i < 4; ++i) {
        int kl = ty + i * 8;
        tile[kl][tx] = __builtin_bit_cast(unsigned short,
                            (__bf16)W1[(size_t)(k0 + kl) * NDIM + n0 + tx]);
    }
    __syncthreads();
#pragma unroll
    for (int i = 0; i < 4; ++i) {
        int nl = ty + i * 8;
        W1T[(size_t)(n0 + nl) * KDIM + k0 + tx] = tile[tx][nl];
    }
}

// ---------------------------------------------------------------------------
// Fused gather-GEMM, T3 double-buffered single-barrier schedule.
// 128x128 tile, BK=64, 8 waves (2M x 4N), wave tile 64x32 (4x2 frags),
// mfma_f32_16x16x32_bf16. LDS 64 KB (dbuf A+B) -> 2 blocks/CU, 4 waves/SIMD.
//  A: gather rows of W0 (fp32) -> regs (issued AFTER the barrier, so never
//     drained by it; consumed just before the next barrier)  [T14]
//  B: global_load_lds width 16 from W1T, pre-swizzled source chunks.
// Per K-step: issueB(next) -> compute(cur) -> writeA(next) -> barrier -> issueA
// ---------------------------------------------------------------------------
__global__ __launch_bounds__(512, 4)
void emb_gemm_ws(const int* __restrict__ idx,
                 const float* __restrict__ W0,
                 const unsigned short* __restrict__ W1T,
                 float* __restrict__ out) {
    __shared__ __align__(16) char A_lds[2][128 * 128];  // [buf][row][64k bf16]
    __shared__ __align__(16) char B_lds[2][128 * 128];

    const int tid  = threadIdx.x;   // 0..511
    const int lane = tid & 63;
    const int wav  = tid >> 6;      // 0..7
    const int wm   = wav >> 2;      // 0..1
    const int wn   = wav & 3;       // 0..3
    const int m0   = blockIdx.x * 128;
    const int n0   = blockIdx.y * 128;

    // ---- A gather setup: 4 rows/thread, one 16B fp32 chunk each ----
    const int achunk = tid & 15;    // 16 chunks cover 64 f32
    const float* aPtr[4];
    int abyte[4];
#pragma unroll
    for (int it = 0; it < 4; ++it) {
        const int r = (tid >> 4) + it * 32;          // 0..127
        aPtr[it]  = W0 + (size_t)idx[m0 + r] * KDIM + achunk * 4;
        abyte[it] = (r * 128 + achunk * 8) ^ ((r & 7) << 4);
    }

    // ---- B staging: 2 gload_lds per thread, pre-swizzled source ----
    const int brin = lane >> 3;          // row within 8-row group
    const int bch  = (lane & 7) ^ brin;  // inverse-swizzled 16B chunk
    const unsigned short* bPtr[2];
    int bbase[2];
#pragma unroll
    for (int i = 0; i < 2; ++i) {
        const int rg = wav * 16 + i * 8;  // wave-uniform group base row
        bPtr[i]  = W1T + (size_t)(n0 + rg + brin) * KDIM + bch * 8;
        bbase[i] = rg * 128;
    }

    f32x4 apre[4];
    auto issueA = [&](int t) {
#pragma unroll
        for (int it = 0; it < 4; ++it)
            apre[it] = *(const f32x4*)(aPtr[it] + t * 64);
    };
    auto writeA = [&](int buf) {
#pragma unroll
        for (int it = 0; it < 4; ++it) {
            uint2 pk;
            pk.x = pkbf(apre[it][0], apre[it][1]);
            pk.y = pkbf(apre[it][2], apre[it][3]);
            *(uint2*)(A_lds[buf] + abyte[it]) = pk;
        }
    };
    auto issueB = [&](int buf, int t) {
#pragma unroll
        for (int i = 0; i < 2; ++i)
            gload_lds16(bPtr[i] + t * 64, B_lds[buf] + bbase[i]);
    };

    f32x4 acc[4][2] = {};
    auto computeT = [&](int buf) {
#pragma unroll
        for (int ks = 0; ks < 2; ++ks) {
            const int kb = ks * 64 + (lane >> 4) * 16;
            bf16x8 af[4], bfv[2];
#pragma unroll
            for (int mi = 0; mi < 4; ++mi) {
                const int r = wm * 64 + mi * 16 + (lane & 15);
                af[mi] = *(const bf16x8*)(A_lds[buf] + ((r * 128 + kb) ^ ((r & 7) << 4)));
            }
#pragma unroll
            for (int ni = 0; ni < 2; ++ni) {
                const int n = wn * 32 + ni * 16 + (lane & 15);
                bfv[ni] = *(const bf16x8*)(B_lds[buf] + ((n * 128 + kb) ^ ((n & 7) << 4)));
            }
#pragma unroll
            for (int mi = 0; mi < 4; ++mi)
#pragma unroll
                for (int ni = 0; ni < 2; ++ni)
                    acc[mi][ni] = __builtin_amdgcn_mfma_f32_16x16x32_bf16(
                        af[mi], bfv[ni], acc[mi][ni], 0, 0, 0);
        }
    };

    // ---- prologue: fill buf0 for tile 0, prefetch A for tile 1 ----
    issueA(0);
    issueB(0, 0);
    writeA(0);              // waits on apre(0)
    __syncthreads();
    issueA(1);

    // ---- main loop: 32 K-steps, single barrier per step ----
    for (int t = 0; t < 31; ++t) {
        const int cur = t & 1, nxt = cur ^ 1;
        issueB(nxt, t + 1);   // in flight across compute; drain at barrier free
        computeT(cur);
        writeA(nxt);          // apre(t+1) long in flight -> cheap wait
        __syncthreads();
        if (t < 30) issueA(t + 2);  // after barrier: never drained by one
    }
    computeT(1);              // tile 31 lives in buf1

    // ---- epilogue: mask (token==0) and scale by 32 = sqrt(1024) ----
    const int col  = lane & 15;
    const int rowq = (lane >> 4) * 4;
#pragma unroll
    for (int mi = 0; mi < 4; ++mi) {
#pragma unroll
        for (int r = 0; r < 4; ++r) {
            const int m = m0 + wm * 64 + mi * 16 + rowq + r;
            const float msk = (idx[m] != 0) ? 32.0f : 0.0f;
#pragma unroll
            for (int ni = 0; ni < 2; ++ni) {
                const int n = n0 + wn * 32 + ni * 16 + col;
                out[(size_t)m * NDIM + n] = acc[mi][ni][r] * msk;
            }
        }
    }
}

// ---------------------------------------------------------------------------
// Fallback (ws too small): single-buffer, transpose-on-stage from W1 fp32.
// ---------------------------------------------------------------------------
__global__ __launch_bounds__(256)
void emb_gemm_nows(const int* __restrict__ idx,
                   const float* __restrict__ W0,
                   const float* __restrict__ W1,
                   float* __restrict__ out) {
    __shared__ __align__(16) char A_lds[128 * 128];
    __shared__ __align__(16) char B_lds[128 * 128];

    const int tid  = threadIdx.x;
    const int lane = tid & 63;
    const int wav  = tid >> 6;
    const int wm = wav >> 1;
    const int wn = wav & 1;
    const int m0 = blockIdx.x * 128;
    const int n0 = blockIdx.y * 128;

    const float* aSrc[8];
    int arow[8];
#pragma unroll
    for (int it = 0; it < 8; ++it) {
        int r = it * 16 + (tid >> 4);
        arow[it] = r;
        aSrc[it] = W0 + (size_t)idx[m0 + r] * KDIM;
    }
    const int acol4 = tid & 15;

    f32x4 acc[4][4] = {};

    for (int k0 = 0; k0 < KDIM; k0 += 64) {
#pragma unroll
        for (int it = 0; it < 8; ++it) {
            const int r = arow[it];
            const float4 v = *(const float4*)(aSrc[it] + k0 + acol4 * 4);
            uint2 pk;
            pk.x = pkbf(v.x, v.y);
            pk.y = pkbf(v.z, v.w);
            *(uint2*)(A_lds + ((r * 128 + acol4 * 8) ^ ((r & 7) << 4))) = pk;
        }
#pragma unroll
        for (int it = 0; it < 8; ++it) {
            const int k  = it * 8 + (tid >> 5);
            const int n4 = (tid & 31) * 4;
            const float4 v = *(const float4*)(W1 + (size_t)(k0 + k) * NDIM + n0 + n4);
            unsigned short h[4] = { f2bf(v.x), f2bf(v.y), f2bf(v.z), f2bf(v.w) };
#pragma unroll
            for (int i = 0; i < 4; ++i) {
                const int n = n4 + i;
                *(unsigned short*)(B_lds + ((n * 128 + k * 2) ^ ((n & 7) << 4))) = h[i];
            }
        }
        __syncthreads();

#pragma unroll
        for (int ks = 0; ks < 2; ++ks) {
            const int kb = ks * 64 + (lane >> 4) * 16;
            bf16x8 af[4], bfv[4];
#pragma unroll
            for (int mi = 0; mi < 4; ++mi) {
                const int r = wm * 64 + mi * 16 + (lane & 15);
                af[mi] = *(const bf16x8*)(A_lds + ((r * 128 + kb) ^ ((r & 7) << 4)));
            }
#pragma unroll
            for (int ni = 0; ni < 4; ++ni) {
                const int n = wn * 64 + ni * 16 + (lane & 15);
                bfv[ni] = *(const bf16x8*)(B_lds + ((n * 128 + kb) ^ ((n & 7) << 4)));
            }
#pragma unroll
            for (int mi = 0; mi < 4; ++mi)
#pragma unroll
                for (int ni = 0; ni < 4; ++ni)
                    acc[mi][ni] = __builtin_amdgcn_mfma_f32_16x16x32_bf16(
                        af[mi], bfv[ni], acc[mi][ni], 0, 0, 0);
        }
        __syncthreads();
    }

    const int col  = lane & 15;
    const int rowq = (lane >> 4) * 4;
#pragma unroll
    for (int mi = 0; mi < 4; ++mi) {
#pragma unroll
        for (int r = 0; r < 4; ++r) {
            const int m = m0 + wm * 64 + mi * 16 + rowq + r;
            const float msk = (idx[m] != 0) ? 32.0f : 0.0f;
#pragma unroll
            for (int ni = 0; ni < 4; ++ni) {
                const int n = n0 + wn * 64 + ni * 16 + col;
                out[(size_t)m * NDIM + n] = acc[mi][ni][r] * msk;
            }
        }
    }
}

extern "C" void kernel_launch(void* const* d_in, const int* in_sizes, int n_in,
                              void* d_out, int out_size, void* d_ws, size_t ws_size,
                              hipStream_t stream) {
    const int*   idx = (const int*)d_in[0];
    const float* W0  = (const float*)d_in[1];
    const float* W1  = (const float*)d_in[2];
    float*       out = (float*)d_out;

    const size_t w1t_bytes = (size_t)KDIM * NDIM * 2;

    if (ws_size >= w1t_bytes) {
        unsigned short* W1T = (unsigned short*)d_ws;
        dim3 tgrid(KDIM / 32, NDIM / 32);
        w1_transpose_kernel<<<tgrid, dim3(32, 8), 0, stream>>>(W1, W1T);
        dim3 grid(MTOK / 128, NDIM / 128);  // (128, 8)
        emb_gemm_ws<<<grid, 512, 0, stream>>>(idx, W0, W1T, out);
    } else {
        dim3 grid(MTOK / 128, NDIM / 128);
        emb_gemm_nows<<<grid, 256, 0, stream>>>(idx, W0, W1, out);
    }
}

// Round 4
// 94.139 us; speedup vs baseline: 1.3190x; 1.2190x over previous
//
#include <hip/hip_runtime.h>
#include <stdint.h>

#define VOCAB 32000
#define KDIM  2048   // 2*HIDDEN
#define NDIM  1024   // HIDDEN
#define MTOK  16384  // 4*4096

typedef __bf16 bf16x8 __attribute__((ext_vector_type(8)));
typedef float  f32x4  __attribute__((ext_vector_type(4)));

// Compiler-lowered f32->bf16 pair (RNE).
__device__ __forceinline__ uint32_t pkbf(float a, float b) {
    union { __bf16 h[2]; uint32_t u; } r;
    r.h[0] = (__bf16)a; r.h[1] = (__bf16)b;
    return r.u;
}

__device__ __forceinline__ unsigned short f2bf(float f) {  // fallback path only
    union { float f; uint32_t u; } v; v.f = f;
    uint32_t u = v.u;
    return (unsigned short)((u + 0x7FFFu + ((u >> 16) & 1u)) >> 16);
}

// width-16 global->LDS DMA: per-lane global src, wave-uniform LDS base.
__device__ __forceinline__ void gload_lds16(const void* g, void* l) {
    __builtin_amdgcn_global_load_lds(
        (const __attribute__((address_space(1))) uint32_t*)g,
        (__attribute__((address_space(3))) uint32_t*)l,
        16, 0, 0);
}

// ---------------------------------------------------------------------------
// One-time transpose+convert: W1 [K][N] f32 -> W1T [N][K] bf16
// ---------------------------------------------------------------------------
__global__ void w1_transpose_kernel(const float* __restrict__ W1,
                                    unsigned short* __restrict__ W1T) {
    __shared__ unsigned short tile[32][33];
    const int k0 = blockIdx.x * 32;
    const int n0 = blockIdx.y * 32;
    const int tx = threadIdx.x;  // 0..31
    const int ty = threadIdx.y;  // 0..7
#pragma unroll
    for (int i = 0; i < 4; ++i) {
        int kl = ty + i * 8;
        tile[kl][tx] = __builtin_bit_cast(unsigned short,
                            (__bf16)W1[(size_t)(k0 + kl) * NDIM + n0 + tx]);
    }
    __syncthreads();
#pragma unroll
    for (int i = 0; i < 4; ++i) {
        int nl = ty + i * 8;
        W1T[(size_t)(n0 + nl) * KDIM + k0 + tx] = tile[tx][nl];
    }
}

// ---------------------------------------------------------------------------
// 256x256-tile fused gather-GEMM, 4-phase-per-K-tile schedule (m201-style).
// BK=64, 512 threads = 8 waves (2M x 4N), wave tile 128x64 (8x4 frags),
// mfma_f32_16x16x32_bf16. LDS 128 KB dbuf -> 1 block/CU, 2 waves/SIMD.
// Per K-tile: ph0{readB(ks0)+readA, issue B(t+1) gload_lds + A(t+1) loads,
//             SB, 16 MFMA, SB} ph1{readA, SB, 16 MFMA, SB}
//             ph2{readB(ks1)+readA, SB, 16 MFMA, SB}
//             ph3{readA, cvt+ds_write A(t+1), 16 MFMA, __syncthreads}
// B issued before A so the compiler's vmcnt wait for A regs subsumes B.
// XOR swizzle byte^=(row&7)<<4 on both tiles; B uses pre-swizzled source.
// ---------------------------------------------------------------------------
__global__ __launch_bounds__(512, 2)
void emb_gemm_ws(const int* __restrict__ idx,
                 const float* __restrict__ W0,
                 const unsigned short* __restrict__ W1T,
                 float* __restrict__ out) {
    __shared__ __align__(16) char Abuf[2][256 * 128];  // 256 rows x 64 bf16
    __shared__ __align__(16) char Bbuf[2][256 * 128];

    const int tid  = threadIdx.x;   // 0..511
    const int lane = tid & 63;
    const int wav  = tid >> 6;      // 0..7
    const int wm   = wav >> 2;      // 0..1  (M half: 128 rows)
    const int wn   = wav & 3;       // 0..3  (N quarter: 64 cols)
    const int m0   = blockIdx.x * 256;
    const int n0   = blockIdx.y * 256;

    // ---- A gather setup: 8 chunks/thread (chunk = 16B fp32 -> 8B bf16) ----
    const int ac = tid & 15;        // 16 chunks cover 64 floats
    const float* aPtr[8];
    int abyte[8];
#pragma unroll
    for (int it = 0; it < 8; ++it) {
        const int r = (tid >> 4) + it * 32;          // 0..255
        aPtr[it]  = W0 + (size_t)idx[m0 + r] * KDIM + ac * 4;
        abyte[it] = (r * 128 + ac * 8) ^ ((r & 7) << 4);
    }

    // ---- B staging: 4 gload_lds/wave (1KB = 8 rows each), pre-swz source ----
    const int brin = lane >> 3;          // row within 8-row group
    const int bch  = (lane & 7) ^ brin;  // inverse-swizzled 16B chunk
    const unsigned short* bPtr[4];
    int bbase[4];
#pragma unroll
    for (int i = 0; i < 4; ++i) {
        const int rg = wav * 32 + i * 8;  // wave-uniform 8-row group base
        bPtr[i]  = W1T + (size_t)(n0 + rg + brin) * KDIM + bch * 8;
        bbase[i] = rg * 128;
    }

    f32x4 apre[8];
    f32x4 acc[8][4] = {};
    bf16x8 bfv[4];

    const int rl = lane & 15;
    const int kq = (lane >> 4) * 16;  // 16B sub-chunk within 64B k-half

#define ISSUE_A(t)                                             \
    _Pragma("unroll")                                          \
    for (int it = 0; it < 8; ++it)                             \
        apre[it] = *(const f32x4*)(aPtr[it] + (t) * 64);

#define WRITE_A(buf)                                           \
    _Pragma("unroll")                                          \
    for (int it = 0; it < 8; ++it) {                           \
        uint2 pk;                                              \
        pk.x = pkbf(apre[it][0], apre[it][1]);                 \
        pk.y = pkbf(apre[it][2], apre[it][3]);                 \
        *(uint2*)(Abuf[buf] + abyte[it]) = pk;                 \
    }

#define ISSUE_B(buf, t)                                        \
    _Pragma("unroll")                                          \
    for (int i = 0; i < 4; ++i)                                \
        gload_lds16(bPtr[i] + (t) * 64, Bbuf[buf] + bbase[i]);

#define READ_B(buf, ks)                                        \
    _Pragma("unroll")                                          \
    for (int ni = 0; ni < 4; ++ni) {                           \
        const int n = wn * 64 + ni * 16 + rl;                  \
        bfv[ni] = *(const bf16x8*)(Bbuf[buf] +                 \
            ((n * 128 + (ks) * 64 + kq) ^ ((n & 7) << 4)));    \
    }

#define READ_A(buf, ks, mh, af)                                \
    _Pragma("unroll")                                          \
    for (int mi = 0; mi < 4; ++mi) {                           \
        const int r = wm * 128 + (mh) * 64 + mi * 16 + rl;     \
        af[mi] = *(const bf16x8*)(Abuf[buf] +                  \
            ((r * 128 + (ks) * 64 + kq) ^ ((r & 7) << 4)));    \
    }

#define MFMA16(mh, af)                                         \
    __builtin_amdgcn_s_setprio(1);                             \
    _Pragma("unroll")                                          \
    for (int mi = 0; mi < 4; ++mi)                             \
        _Pragma("unroll")                                      \
        for (int ni = 0; ni < 4; ++ni)                         \
            acc[(mh) * 4 + mi][ni] =                           \
                __builtin_amdgcn_mfma_f32_16x16x32_bf16(       \
                    af[mi], bfv[ni], acc[(mh) * 4 + mi][ni], 0, 0, 0); \
    __builtin_amdgcn_s_setprio(0);

    // ---- prologue: stage K-tile 0 into buf0 ----
    ISSUE_B(0, 0);
    ISSUE_A(0);
    WRITE_A(0);        // compiler inserts vmcnt wait for apre (subsumes B)
    __syncthreads();   // full drain + barrier: tile 0 ready

    // ---- main loop: 32 K-tiles ----
    for (int t = 0; t < 32; ++t) {
        const int cur = t & 1, nxt = cur ^ 1;
        const bool pf = (t < 31);
        bf16x8 af[4];

        // phase 0: ks=0, m-half 0; issue next tile's loads (B first, then A)
        READ_B(cur, 0);
        READ_A(cur, 0, 0, af);
        if (pf) { ISSUE_B(nxt, t + 1); ISSUE_A(t + 1); }
        __builtin_amdgcn_s_barrier();
        MFMA16(0, af);
        __builtin_amdgcn_s_barrier();

        // phase 1: ks=0, m-half 1 (reuse bfv)
        READ_A(cur, 0, 1, af);
        __builtin_amdgcn_s_barrier();
        MFMA16(1, af);
        __builtin_amdgcn_s_barrier();

        // phase 2: ks=1, m-half 0
        READ_B(cur, 1);
        READ_A(cur, 1, 0, af);
        __builtin_amdgcn_s_barrier();
        MFMA16(0, af);
        __builtin_amdgcn_s_barrier();

        // phase 3: ks=1, m-half 1; convert+write A(t+1) (loads ~3 phases old)
        READ_A(cur, 1, 1, af);
        if (pf) { WRITE_A(nxt); }
        __builtin_amdgcn_s_barrier();
        MFMA16(1, af);
        // boundary: drain (vmcnt already ~0 after WRITE_A's wait) + flip
        __syncthreads();
    }

    // ---- epilogue: mask (token==0) and scale by 32 = sqrt(1024) ----
    const int rowq = (lane >> 4) * 4;
#pragma unroll
    for (int mi = 0; mi < 8; ++mi) {
#pragma unroll
        for (int r = 0; r < 4; ++r) {
            const int m = m0 + wm * 128 + mi * 16 + rowq + r;
            const float msk = (idx[m] != 0) ? 32.0f : 0.0f;
#pragma unroll
            for (int ni = 0; ni < 4; ++ni) {
                const int n = n0 + wn * 64 + ni * 16 + rl;
                out[(size_t)m * NDIM + n] = acc[mi][ni][r] * msk;
            }
        }
    }
#undef ISSUE_A
#undef WRITE_A
#undef ISSUE_B
#undef READ_B
#undef READ_A
#undef MFMA16
}

// ---------------------------------------------------------------------------
// Fallback (ws too small): single-buffer, transpose-on-stage from W1 fp32.
// ---------------------------------------------------------------------------
__global__ __launch_bounds__(256)
void emb_gemm_nows(const int* __restrict__ idx,
                   const float* __restrict__ W0,
                   const float* __restrict__ W1,
                   float* __restrict__ out) {
    __shared__ __align__(16) char A_lds[128 * 128];
    __shared__ __align__(16) char B_lds[128 * 128];

    const int tid  = threadIdx.x;
    const int lane = tid & 63;
    const int wav  = tid >> 6;
    const int wm = wav >> 1;
    const int wn = wav & 1;
    const int m0 = blockIdx.x * 128;
    const int n0 = blockIdx.y * 128;

    const float* aSrc[8];
    int arow[8];
#pragma unroll
    for (int it = 0; it < 8; ++it) {
        int r = it * 16 + (tid >> 4);
        arow[it] = r;
        aSrc[it] = W0 + (size_t)idx[m0 + r] * KDIM;
    }
    const int acol4 = tid & 15;

    f32x4 acc[4][4] = {};

    for (int k0 = 0; k0 < KDIM; k0 += 64) {
#pragma unroll
        for (int it = 0; it < 8; ++it) {
            const int r = arow[it];
            const float4 v = *(const float4*)(aSrc[it] + k0 + acol4 * 4);
            uint2 pk;
            pk.x = pkbf(v.x, v.y);
            pk.y = pkbf(v.z, v.w);
            *(uint2*)(A_lds + ((r * 128 + acol4 * 8) ^ ((r & 7) << 4))) = pk;
        }
#pragma unroll
        for (int it = 0; it < 8; ++it) {
            const int k  = it * 8 + (tid >> 5);
            const int n4 = (tid & 31) * 4;
            const float4 v = *(const float4*)(W1 + (size_t)(k0 + k) * NDIM + n0 + n4);
            unsigned short h[4] = { f2bf(v.x), f2bf(v.y), f2bf(v.z), f2bf(v.w) };
#pragma unroll
            for (int i = 0; i < 4; ++i) {
                const int n = n4 + i;
                *(unsigned short*)(B_lds + ((n * 128 + k * 2) ^ ((n & 7) << 4))) = h[i];
            }
        }
        __syncthreads();

#pragma unroll
        for (int ks = 0; ks < 2; ++ks) {
            const int kb = ks * 64 + (lane >> 4) * 16;
            bf16x8 af[4], bfv[4];
#pragma unroll
            for (int mi = 0; mi < 4; ++mi) {
                const int r = wm * 64 + mi * 16 + (lane & 15);
                af[mi] = *(const bf16x8*)(A_lds + ((r * 128 + kb) ^ ((r & 7) << 4)));
            }
#pragma unroll
            for (int ni = 0; ni < 4; ++ni) {
                const int n = wn * 64 + ni * 16 + (lane & 15);
                bfv[ni] = *(const bf16x8*)(B_lds + ((n * 128 + kb) ^ ((n & 7) << 4)));
            }
#pragma unroll
            for (int mi = 0; mi < 4; ++mi)
#pragma unroll
                for (int ni = 0; ni < 4; ++ni)
                    acc[mi][ni] = __builtin_amdgcn_mfma_f32_16x16x32_bf16(
                        af[mi], bfv[ni], acc[mi][ni], 0, 0, 0);
        }
        __syncthreads();
    }

    const int col  = lane & 15;
    const int rowq = (lane >> 4) * 4;
#pragma unroll
    for (int mi = 0; mi < 4; ++mi) {
#pragma unroll
        for (int r = 0; r < 4; ++r) {
            const int m = m0 + wm * 64 + mi * 16 + rowq + r;
            const float msk = (idx[m] != 0) ? 32.0f : 0.0f;
#pragma unroll
            for (int ni = 0; ni < 4; ++ni) {
                const int n = n0 + wn * 64 + ni * 16 + col;
                out[(size_t)m * NDIM + n] = acc[mi][ni][r] * msk;
            }
        }
    }
}

extern "C" void kernel_launch(void* const* d_in, const int* in_sizes, int n_in,
                              void* d_out, int out_size, void* d_ws, size_t ws_size,
                              hipStream_t stream) {
    const int*   idx = (const int*)d_in[0];
    const float* W0  = (const float*)d_in[1];
    const float* W1  = (const float*)d_in[2];
    float*       out = (float*)d_out;

    const size_t w1t_bytes = (size_t)KDIM * NDIM * 2;

    if (ws_size >= w1t_bytes) {
        unsigned short* W1T = (unsigned short*)d_ws;
        dim3 tgrid(KDIM / 32, NDIM / 32);
        w1_transpose_kernel<<<tgrid, dim3(32, 8), 0, stream>>>(W1, W1T);
        dim3 grid(MTOK / 256, NDIM / 256);  // (64, 4) = 256 blocks = 1/CU
        emb_gemm_ws<<<grid, 512, 0, stream>>>(idx, W0, W1T, out);
    } else {
        dim3 grid(MTOK / 128, NDIM / 128);
        emb_gemm_nows<<<grid, 256, 0, stream>>>(idx, W0, W1, out);
    }
}